// Round 1
// baseline (400.007 us; speedup 1.0000x reference)
//
#include <hip/hip_runtime.h>
#include <hip/hip_bf16.h>

// Problem constants: B=16, N=4096 -> NTOK=65536, DIM=1024, T=8, E=64
#define NTOK  65536
#define DIM_  1024
#define NHEAD 8
#define EOUT  64
#define KBLK  32          // DIM_/32 k-steps of the 16x16x32 MFMA
#define CNT_STRIDE 32     // pad each head counter to its own 128B line

typedef __bf16 bf16x8 __attribute__((ext_vector_type(8)));
typedef float  f32x4  __attribute__((ext_vector_type(4)));
typedef unsigned short u16x8 __attribute__((ext_vector_type(8)));

__device__ inline __bf16 cvt_bf16(float f) {
    __hip_bfloat16 h = __float2bfloat16(f);
    return __builtin_bit_cast(__bf16, h);
}

// Async global->LDS, 16B per lane. LDS dest = wave-uniform base + lane*16.
__device__ inline void gload_lds16(const void* g, void* lds) {
    __builtin_amdgcn_global_load_lds(
        (const __attribute__((address_space(1))) unsigned int*)g,
        (__attribute__((address_space(3))) unsigned int*)lds,
        16, 0, 0);
}

// ---------------------------------------------------------------------------
// Kernel 0 (unchanged, verified): pack W fp32 -> bf16 MFMA B-fragment order,
// AND bucket tokens by head (blocks 0..63; one atomic per head per wave).
// Wp flat index: (((t*KBLK + kb)*4 + et)*64 + lane)*8 + j
//   holds W[t][kb*32 + (lane>>4)*8 + j][et*16 + (lane&15)]
// ---------------------------------------------------------------------------
__global__ __launch_bounds__(256) void pack_and_bucket(
    const float* __restrict__ W, const int* __restrict__ idx,
    unsigned short* __restrict__ Wp, int* __restrict__ cnt,
    int* __restrict__ list)
{
    int x = blockIdx.x * blockDim.x + threadIdx.x;
    {
        int j  = x & 7;
        int l  = (x >> 3) & 63;
        int et = (x >> 9) & 3;
        int kb = (x >> 11) & 31;
        int t  = x >> 16;
        int k = kb * 32 + (l >> 4) * 8 + j;
        int e = et * 16 + (l & 15);
        float v = W[((size_t)t * DIM_ + k) * EOUT + e];
        __hip_bfloat16 h = __float2bfloat16(v);
        Wp[x] = __builtin_bit_cast(unsigned short, h);
    }

    if (blockIdx.x < NTOK / 1024) {
        int wave = threadIdx.x >> 6;
        int lane = threadIdx.x & 63;
        int gw   = blockIdx.x * 4 + wave;        // 256 waves total
        int tbase = gw * 256;
        int t[4];
        #pragma unroll
        for (int c = 0; c < 4; ++c) t[c] = idx[tbase + c * 64 + lane];

        #pragma unroll
        for (int h = 0; h < NHEAD; ++h) {
            unsigned long long m[4];
            int nh = 0;
            #pragma unroll
            for (int c = 0; c < 4; ++c) {
                m[c] = __ballot(t[c] == h);
                nh += __popcll(m[c]);
            }
            int base = 0;
            if (lane == 0 && nh) base = atomicAdd(&cnt[h * CNT_STRIDE], nh);
            base = __shfl(base, 0, 64);
            int pre = 0;
            #pragma unroll
            for (int c = 0; c < 4; ++c) {
                if (t[c] == h) {
                    int rank = __popcll(m[c] & ((1ull << lane) - 1ull));
                    list[h * NTOK + base + pre + rank] = tbase + c * 64 + lane;
                }
                pre += __popcll(m[c]);
            }
        }
    }
}

// ---------------------------------------------------------------------------
// Kernel 1: gathered GEMM, restructured for latency hiding.
//   One block (4 waves) per 32-token tile. The block cooperatively streams
//   the gathered A rows (32 tokens x 1024 f32 = 128KB) through a 4-deep
//   async global_load_lds pipeline (8KB chunks = 2 k-blocks), counted vmcnt
//   (never 0 mid-loop), raw s_barrier. Waves split the output: wave(rg,ep)
//   computes row-group rg (16 rows) x E-half ep (2 et fragments).
//   LDS staging is linear (global_load_lds constraint); bank conflicts on the
//   strided f32x4 reads are killed by pre-swizzling the GLOBAL source column
//   (cu ^ (row&15)) and reading with the same XOR.
//   B fragments (L2-resident packed Wp) are prefetched 1 chunk ahead to regs.
// Per-wave vm-op pattern/iter: 4x B-load, 2x global_load_lds.
// Steady wait = vmcnt(8)  (keeps 2 staged chunks + next B in flight).
// ---------------------------------------------------------------------------
__global__ __launch_bounds__(256, 4) void readout_gemm(
    const float* __restrict__ emb, const float* __restrict__ bias,
    const int* __restrict__ cnt, const int* __restrict__ list,
    const unsigned short* __restrict__ Wp, float* __restrict__ out)
{
    __shared__ __align__(16) char smem[4 * 8192];   // 4 bufs x (32 rows x 256B)

    // Map block -> (head, tile) via prefix of per-head tile counts
    int g = blockIdx.x;
    int head = -1, tile = 0, count = 0, total = 0;
    #pragma unroll
    for (int h = 0; h < NHEAD; ++h) {
        int c = cnt[h * CNT_STRIDE];
        int th = (c + 31) >> 5;
        if (head < 0 && g < total + th) { head = h; tile = g - total; count = c; }
        total += th;
    }
    if (head < 0) return;   // uniform across block

    int wave = threadIdx.x >> 6;
    int lane = threadIdx.x & 63;
    int quad = lane >> 4, l16 = lane & 15;
    int rg = wave >> 1;       // row-group 0/1 (16 rows each)
    int ep = wave & 1;        // E-half: ets {ep*2, ep*2+1}
    int eb = ep * 2;

    const int* mylist = list + head * NTOK;
    int mbase = tile * 32;

    // ---- staging source (per lane): unit u = wave*128 + i*64 + lane ----
    // row = u>>4 = wave*8 + i*4 + quad ; col unit = l16 ; global col = l16 ^ (row&15)
    int srow0 = wave * 8 + quad;
    int srow1 = srow0 + 4;
    int sm0 = mbase + srow0; if (sm0 > count - 1) sm0 = count - 1;
    int sm1 = mbase + srow1; if (sm1 > count - 1) sm1 = count - 1;
    const char* gs0 = (const char*)(emb + (size_t)mylist[sm0] * DIM_)
                      + ((l16 ^ (srow0 & 15)) * 16);
    const char* gs1 = (const char*)(emb + (size_t)mylist[sm1] * DIM_)
                      + ((l16 ^ (srow1 & 15)) * 16);
    char* ldsw = smem + wave * 2048;            // + buf*8192 (+ i*1024)

    // ---- A-fragment read base: row = rg*16 + l16, swizzled col ----
    int arow = rg * 16 + l16;                   // arow & 15 == l16

    // ---- B fragments from L2-resident Wp ----
    const u16x8* wp = reinterpret_cast<const u16x8*>(Wp + (size_t)head * 65536);

    // ---- prologue: B(0) to regs; stage chunks 0..2 ----
    u16x8 BA[2][2], BB[2][2];
    #pragma unroll
    for (int kk = 0; kk < 2; ++kk)
        #pragma unroll
        for (int e = 0; e < 2; ++e)
            BA[kk][e] = wp[(kk * 4 + eb + e) * 64 + lane];

    #pragma unroll
    for (int s = 0; s < 3; ++s) {
        char* d = ldsw + s * 8192;
        gload_lds16(gs0 + s * 256, d);
        gload_lds16(gs1 + s * 256, d + 1024);
    }

    f32x4 acc[2] = {};

    // ---- pipelined main loop over 16 chunks (2 k-blocks each) ----
    auto body = [&](int c, u16x8 (&Bc)[2][2], u16x8 (&Bn)[2][2]) {
        // prefetch B(c+1) into regs (L2 hit, used next iter)
        if (c + 1 < 16) {
            #pragma unroll
            for (int kk = 0; kk < 2; ++kk)
                #pragma unroll
                for (int e = 0; e < 2; ++e)
                    Bn[kk][e] = wp[((2 * (c + 1) + kk) * 4 + eb + e) * 64 + lane];
        }
        // barrier 1: all waves finished reading chunk c-1 -> safe to overwrite
        asm volatile("s_waitcnt lgkmcnt(0)" ::: "memory");
        __builtin_amdgcn_s_barrier();
        // stage chunk c+3 into buf (c+3)&3 (== buf of chunk c-1)
        if (c + 3 < 16) {
            char* d = ldsw + ((c + 3) & 3) * 8192;
            gload_lds16(gs0 + (c + 3) * 256, d);
            gload_lds16(gs1 + (c + 3) * 256, d + 1024);
        }
        // counted wait: drains through B(c) (and S(c)); leaves S(c+2),S(c+3),B(c+1)
        if (c < 13)       asm volatile("s_waitcnt vmcnt(8)" ::: "memory");
        else if (c == 13) asm volatile("s_waitcnt vmcnt(6)" ::: "memory");
        else if (c == 14) asm volatile("s_waitcnt vmcnt(4)" ::: "memory");
        else              asm volatile("s_waitcnt vmcnt(0)" ::: "memory");
        __builtin_amdgcn_s_barrier();   // chunk c visible to all waves

        // consume chunk c: 2 k-blocks x (2 ds_read_b128 + cvt + 2 MFMA)
        const char* bb = smem + (c & 3) * 8192 + arow * 256;
        #pragma unroll
        for (int kk = 0; kk < 2; ++kk) {
            int cu0 = kk * 8 + quad * 2;
            f32x4 lo = *(const f32x4*)(bb + (((cu0 + 0) ^ l16) * 16));
            f32x4 hi = *(const f32x4*)(bb + (((cu0 + 1) ^ l16) * 16));
            bf16x8 a;
            #pragma unroll
            for (int j = 0; j < 4; ++j) {
                a[j]     = cvt_bf16(lo[j]);
                a[j + 4] = cvt_bf16(hi[j]);
            }
            #pragma unroll
            for (int e = 0; e < 2; ++e)
                acc[e] = __builtin_amdgcn_mfma_f32_16x16x32_bf16(
                    a, __builtin_bit_cast(bf16x8, Bc[kk][e]), acc[e], 0, 0, 0);
        }
    };

    #pragma unroll 8
    for (int c = 0; c < 16; c += 2) {
        body(c,     BA, BB);
        body(c + 1, BB, BA);
    }

    // ---- epilogue: C layout col=lane&15, row=(lane>>4)*4+i. Scatter + bias.
    int tok[4];
    #pragma unroll
    for (int i = 0; i < 4; ++i) {
        int m = mbase + rg * 16 + quad * 4 + i;
        tok[i] = (m < count) ? mylist[m] : -1;
    }
    #pragma unroll
    for (int e = 0; e < 2; ++e) {
        float bv = bias[head * EOUT + (eb + e) * 16 + l16];
        #pragma unroll
        for (int i = 0; i < 4; ++i)
            if (tok[i] >= 0)
                __builtin_nontemporal_store(acc[e][i] + bv,
                    &out[(size_t)tok[i] * EOUT + (eb + e) * 16 + l16]);
    }
}

// ---------------------------------------------------------------------------
// ws layout: [0,1024)                  cnt (8 ints @ 128B stride, zeroed/call)
//            [1024, 1024+2MB)          per-head token lists
//            [1024+2MB, 1024+2MB+1MB)  packed bf16 W fragments
// ---------------------------------------------------------------------------
extern "C" void kernel_launch(void* const* d_in, const int* in_sizes, int n_in,
                              void* d_out, int out_size, void* d_ws, size_t ws_size,
                              hipStream_t stream) {
    const float* emb  = (const float*)d_in[0];
    const int*   idx  = (const int*)d_in[1];
    const float* W    = (const float*)d_in[2];
    const float* bias = (const float*)d_in[3];
    float* out = (float*)d_out;

    char* ws = (char*)d_ws;
    int* cnt  = (int*)ws;
    int* list = (int*)(ws + 1024);
    unsigned short* Wp = (unsigned short*)(ws + 1024 + (size_t)NHEAD * NTOK * sizeof(int));

    (void)hipMemsetAsync(cnt, 0, NHEAD * CNT_STRIDE * sizeof(int), stream);
    pack_and_bucket<<<(NHEAD * KBLK * 4 * 64 * 8) / 256, 256, 0, stream>>>(W, idx, Wp, cnt, list);
    // one block per tile; max tiles = sum_h ceil(cnt[h]/32) <= 2048 + 7 = 2055
    readout_gemm<<<2055, 256, 0, stream>>>(emb, bias, cnt, list, Wp, out);
}